// Round 6
// baseline (199.179 us; speedup 1.0000x reference)
//
#include <hip/hip_runtime.h>
#include <hip/hip_fp16.h>

// ---------------- types ----------------
typedef _Float16 half8_t __attribute__((ext_vector_type(8)));
typedef _Float16 half4_t __attribute__((ext_vector_type(4)));
typedef _Float16 h2      __attribute__((ext_vector_type(2)));
typedef float    f32x4   __attribute__((ext_vector_type(4)));

#define LOG2E 1.4426950408889634f
// SCALE = 1/sqrt(32); fold log2(e) so we can use exp2
#define KSCALE (0.17677669529663687f * LOG2E)

#if __has_builtin(__builtin_amdgcn_exp2f)
#define EXP2F(x) __builtin_amdgcn_exp2f(x)
#else
#define EXP2F(x) exp2f(x)
#endif

// DPP row_ror:N (rotate within 16-lane row) — VALU cross-lane, no LDS pipe.
template <int N>
__device__ __forceinline__ int dpp_ror(int v) {
  return __builtin_amdgcn_update_dpp(0, v, 0x120 + N, 0xf, 0xf, true);
}
// 16-lane max-reduce of two independent f16 values packed in h2.
__device__ __forceinline__ h2 rowmax16_h2(h2 v) {
  int t;
  t = dpp_ror<1>(__builtin_bit_cast(int, v));
  v = __builtin_elementwise_max(v, __builtin_bit_cast(h2, t));
  t = dpp_ror<2>(__builtin_bit_cast(int, v));
  v = __builtin_elementwise_max(v, __builtin_bit_cast(h2, t));
  t = dpp_ror<4>(__builtin_bit_cast(int, v));
  v = __builtin_elementwise_max(v, __builtin_bit_cast(h2, t));
  t = dpp_ror<8>(__builtin_bit_cast(int, v));
  v = __builtin_elementwise_max(v, __builtin_bit_cast(h2, t));
  return v;
}

// ---------------------------------------------------------------------------
// prep: [0,1024)   x -> f16 (vector cast)
//       [1024,1072) Wqkv^T via LDS 64x64 tile transpose (4 k-tiles x 12 o-tiles)
//       [1072,1088) Wout^T via LDS tile transpose (16 tiles)
//       [1088,1104) coords layer-1 precompute
// ---------------------------------------------------------------------------
__global__ __launch_bounds__(256) void prep_misc(
    const float* __restrict__ x, const float* __restrict__ Wqkv,
    const float* __restrict__ Wout, const float* __restrict__ coords,
    const float* __restrict__ pw1, const float* __restrict__ pb1,
    const float* __restrict__ sw1, const float* __restrict__ sb1,
    _Float16* __restrict__ xf16, _Float16* __restrict__ WqkvT,
    _Float16* __restrict__ WoutT, _Float16* __restrict__ APre,
    _Float16* __restrict__ BPre)
{
  __shared__ float tile[64][65];
  const int bi = blockIdx.x, tid = threadIdx.x;
  if (bi < 1024) {                       // x cast: 1,048,576 floats
    const int idx = bi * 256 + tid;
    f32x4 v = *reinterpret_cast<const f32x4*>(x + idx * 4);
    half4_t h;
    h[0] = (_Float16)v[0]; h[1] = (_Float16)v[1];
    h[2] = (_Float16)v[2]; h[3] = (_Float16)v[3];
    *reinterpret_cast<half4_t*>(xf16 + idx * 4) = h;
  } else if (bi < 1088) {                // W transposes, 64x64 tiles
    const float* src; _Float16* dst; int t, W;  // W = src row width
    if (bi < 1072) { t = bi - 1024; src = Wqkv; dst = WqkvT; W = 768; }
    else           { t = bi - 1072; src = Wout; dst = WoutT; W = 256; }
    const int nOT = W >> 6;              // o-tiles per k-row
    const int tk = t / nOT, to = t % nOT;
    const int cx = tid & 63, ry = tid >> 6;
#pragma unroll
    for (int rr = 0; rr < 16; ++rr) {
      const int kl = rr * 4 + ry;
      tile[kl][cx] = src[(tk * 64 + kl) * W + to * 64 + cx];
    }
    __syncthreads();
#pragma unroll
    for (int rr = 0; rr < 16; ++rr) {
      const int ol = rr * 4 + ry;
      dst[(to * 64 + ol) * 256 + tk * 64 + cx] = (_Float16)tile[cx][ol];
    }
  } else {                               // coords precompute: 4096 rows
    const int row = (bi - 1088) * 256 + tid;
    const float c0 = coords[row * 3 + 0];
    const float c1 = coords[row * 3 + 1];
    const float c2 = coords[row * 3 + 2];
#pragma unroll
    for (int k = 0; k < 16; ++k) {
      float a = c0 * pw1[k] + c1 * pw1[16 + k] + c2 * pw1[32 + k];
      APre[row * 32 + k] = (_Float16)(a + pb1[k]);
      BPre[row * 32 + k] = (_Float16)a;
      float s  =  c0 * sw1[k] + c1 * sw1[16 + k] + c2 * sw1[32 + k];
      float sb = -c0 * sw1[k] + c1 * sw1[16 + k] + c2 * sw1[32 + k];
      APre[row * 32 + 16 + k] = (_Float16)(s + sb1[k]);
      BPre[row * 32 + 16 + k] = (_Float16)sb;
    }
  }
}

// ---------------------------------------------------------------------------
// qkv_gemm: [4096x768] = xf16[4096x256] @ Wqkv; wave does 16i x 64o (4 tiles,
// A-fragment reused 4x). Epilogue: Q/K coalesced scatter (32B segments);
// V THIS ROUND goes through a per-wave LDS transpose so Vt [B][H][32d][2048n]
// is written as per-lane 16B row segments instead of 2B scatters (the old
// pattern hit 64 distinct rows per store instruction).
// ---------------------------------------------------------------------------
__global__ __launch_bounds__(256) void qkv_gemm(
    const _Float16* __restrict__ xf16, const _Float16* __restrict__ WqkvT,
    _Float16* __restrict__ Qh, _Float16* __restrict__ Kh,
    _Float16* __restrict__ Vt)
{
  __shared__ _Float16 vtile[4][64][24];   // per-wave 64o x 16n tile, stride 24 (48B, 16B-aligned)
  const int wv = threadIdx.x >> 6;
  const int wg = blockIdx.x * 4 + wv;
  const int ti = wg / 12, og = wg % 12;
  const int i0 = ti * 16, o0 = og * 64;
  const int lane = threadIdx.x & 63, q = lane >> 4, c = lane & 15;
  f32x4 acc[4] = {{0,0,0,0},{0,0,0,0},{0,0,0,0},{0,0,0,0}};
  const _Float16* arow = xf16 + (i0 + c) * 256;
  const _Float16* brow = WqkvT + (o0 + c) * 256;
#pragma unroll
  for (int k0 = 0; k0 < 256; k0 += 32) {
    half8_t af = *reinterpret_cast<const half8_t*>(arow + k0 + q * 8);
#pragma unroll
    for (int t = 0; t < 4; ++t) {
      half8_t bf = *reinterpret_cast<const half8_t*>(brow + t * 16 * 256 + k0 + q * 8);
      acc[t] = __builtin_amdgcn_mfma_f32_16x16x32_f16(af, bf, acc[t], 0, 0, 0);
    }
  }
  const int b = i0 >> 11, n0 = i0 & 2047;
  if (og < 8) {                          // Q / K epilogue (unchanged)
#pragma unroll
    for (int t = 0; t < 4; ++t) {
      const int o = o0 + t * 16 + c;
      const int which = o >> 8, h = (o >> 5) & 7, d = o & 31;
#pragma unroll
      for (int r = 0; r < 4; ++r) {
        const int n = n0 + q * 4 + r;
        _Float16 v = (_Float16)acc[t][r];
        if (which == 0) Qh[((b * 8 + h) * 2048 + n) * 32 + d] = v;
        else            Kh[((b * 8 + h) * 2048 + n) * 32 + d] = v;
      }
    }
  } else {                               // V epilogue via LDS transpose
    _Float16* vt = &vtile[wv][0][0];
#pragma unroll
    for (int t = 0; t < 4; ++t)
#pragma unroll
      for (int r = 0; r < 4; ++r)
        vt[(t * 16 + c) * 24 + q * 4 + r] = (_Float16)acc[t][r];
    asm volatile("s_waitcnt lgkmcnt(0)" ::: "memory");   // wave-private tile
    __builtin_amdgcn_sched_barrier(0);
    // row = (b*8 + h)*32 + d  ==  b*256 + (o-512), o = o0 + lane
    const long row = (long)(b * 256 + (o0 - 512) + lane);
    half8_t r0 = *reinterpret_cast<const half8_t*>(vt + lane * 24);
    half8_t r1 = *reinterpret_cast<const half8_t*>(vt + lane * 24 + 8);
    *reinterpret_cast<half8_t*>(Vt + row * 2048 + n0)     = r0;
    *reinterpret_cast<half8_t*>(Vt + row * 2048 + n0 + 8) = r1;
  }
}

// ---------------------------------------------------------------------------
// flash: grid = [b:2][chunk:4][itile:64]; block = 512 thr, wave w = head w.
// Two 16-row Q streams A/B per wave. THIS ROUND (issue-bound per r3/r5
// occupancy experiments — cut instructions / deepen per-wave ILP):
//   * j-tile PAIR unroll (KVBLK=64): bias for both tiles written to both
//     dbuf halves -> ONE barrier per 2 tiles; K/V loads + 8 score MFMAs
//     batched; 4 softmax chains interleave; 8 PV MFMAs clustered.
//   * lp via ones-MFMA: row-sum of P on the matrix pipe (kills 16 VALU
//     adds/tile + the entire epilogue rowsum16 reduce; denominator now
//     uses the identical f16 P as the numerator).
//   * threadfence -> targeted s_waitcnt lgkmcnt(0) + sched_barrier(0).
// NOTE: __launch_bounds__(512,4) — (512,6) spilled (round-4, unified
// VGPR/AGPR file). Do not raise waves/EU.
// ---------------------------------------------------------------------------
__global__ __launch_bounds__(512, 4) void flash(
    const _Float16* __restrict__ Qh, const _Float16* __restrict__ Kh,
    const _Float16* __restrict__ Vt, const _Float16* __restrict__ APre,
    const _Float16* __restrict__ BPre, const float* __restrict__ pw2,
    const float* __restrict__ sw2, _Float16* __restrict__ Opart,
    float* __restrict__ Mpart)
{
  __shared__ __align__(16) unsigned char smem[69888];
  _Float16* biasH = reinterpret_cast<_Float16*>(smem);          // [2][8h*1160] f16
  _Float16* pbuf  = reinterpret_cast<_Float16*>(smem + 37120);  // [8w][4][512] f16

  const int blk = blockIdx.x;
  const int b     = blk >> 8;
  const int chunk = (blk >> 6) & 3;
  const int i0    = (blk & 63) << 5;
  const int tid = threadIdx.x;
  const int w = tid >> 6, lane = tid & 63;
  const int q = lane >> 4, c = lane & 15;

  // Q fragments (A-operand): stream A rows i0+c, stream B rows i0+16+c
  const _Float16* qbase = Qh + ((b * 8 + w) * 2048 + i0) * 32;
  half8_t qfA = *reinterpret_cast<const half8_t*>(qbase + c * 32 + q * 8);
  half8_t qfB = *reinterpret_cast<const half8_t*>(qbase + (16 + c) * 32 + q * 8);
  // APre fragments for bias-MFMA A side, j-invariant
  const _Float16* abase = APre + (b * 2048 + i0) * 32;
  half8_t apfA = *reinterpret_cast<const half8_t*>(abase + c * 32 + q * 8);
  half8_t apfB = *reinterpret_cast<const half8_t*>(abase + (16 + c) * 32 + q * 8);

  // stacked W2 B-fragment: B[k][n], k<16 -> pos_w2, k>=16 -> sym_w2; *LOG2E
  half8_t w2f;
#pragma unroll
  for (int jj = 0; jj < 8; ++jj) {
    const int k = q * 8 + jj;
    float val = 0.f;
    if (c < 8) val = (k < 16 ? pw2[k * 8 + c] : sw2[(k - 16) * 8 + c]) * LOG2E;
    w2f[jj] = (_Float16)val;
  }
  half8_t ones8;
#pragma unroll
  for (int jj = 0; jj < 8; ++jj) ones8[jj] = (_Float16)1.0f;

  float mA[4], mB[4];
  f32x4 O0A = {0,0,0,0}, O1A = {0,0,0,0}, O0B = {0,0,0,0}, O1B = {0,0,0,0};
  f32x4 lpA = {0,0,0,0}, lpB = {0,0,0,0};
#pragma unroll
  for (int r = 0; r < 4; ++r) { mA[r] = 0.f; mB[r] = 0.f; }  // m init 0 (exact)

  const f32x4 z4 = {0.f, 0.f, 0.f, 0.f};
  half8_t hzero8 = {};

  const int jbase = chunk * 512;
  const _Float16* BPre_b = BPre + (long)b * 2048 * 32;
  _Float16* pb = pbuf + w * 2048;   // regions: A0=+0, A1=+512, B0=+1024, B1=+1536

  for (int pt = 0; pt < 8; ++pt) {
    const int j0 = jbase + pt * 64;

    // ---- bias: tile0 -> buf0, tile1 -> buf1 (8 mt-MFMAs, both i-halves) ----
#pragma unroll
    for (int half = 0; half < 2; ++half) {
      _Float16* bW = biasH + half * 9280;
      const int jj0 = j0 + half * 32;
#pragma unroll
      for (int mt = 0; mt < 4; ++mt) {
        const int jl = w * 4 + mt;
        half8_t bpf = *reinterpret_cast<const half8_t*>(
            BPre_b + (jj0 + jl) * 32 + q * 8);
        half8_t hvA = __builtin_elementwise_max(apfA - bpf, hzero8);
        f32x4 bcA = __builtin_amdgcn_mfma_f32_16x16x32_f16(hvA, w2f, z4, 0, 0, 0);
        half8_t hvB = __builtin_elementwise_max(apfB - bpf, hzero8);
        f32x4 bcB = __builtin_amdgcn_mfma_f32_16x16x32_f16(hvB, w2f, z4, 0, 0, 0);
        if (c < 8) {   // [h][j][i], j-stride 36, h-stride 1160
          half4_t b4;
          b4[0] = (_Float16)bcA[0]; b4[1] = (_Float16)bcA[1];
          b4[2] = (_Float16)bcA[2]; b4[3] = (_Float16)bcA[3];
          *reinterpret_cast<half4_t*>(bW + c * 1160 + jl * 36 + q * 4) = b4;
          half4_t b5;
          b5[0] = (_Float16)bcB[0]; b5[1] = (_Float16)bcB[1];
          b5[2] = (_Float16)bcB[2]; b5[3] = (_Float16)bcB[3];
          *reinterpret_cast<half4_t*>(bW + c * 1160 + jl * 36 + 16 + q * 4) = b5;
        }
      }
    }

    // ---- K/V fragments + scores, BOTH tiles (batched ahead of barrier) ----
    const _Float16* kbase = Kh + ((b * 8 + w) * 2048 + j0) * 32;
    const _Float16* vbase = Vt + (b * 8 + w) * 65536 + j0;
    half8_t kf00 = *reinterpret_cast<const half8_t*>(kbase + (2 * c) * 32 + q * 8);
    half8_t kf01 = *reinterpret_cast<const half8_t*>(kbase + (2 * c + 1) * 32 + q * 8);
    half8_t kf10 = *reinterpret_cast<const half8_t*>(kbase + (32 + 2 * c) * 32 + q * 8);
    half8_t kf11 = *reinterpret_cast<const half8_t*>(kbase + (32 + 2 * c + 1) * 32 + q * 8);
    half8_t vf00 = *reinterpret_cast<const half8_t*>(vbase + c * 2048 + q * 8);
    half8_t vf01 = *reinterpret_cast<const half8_t*>(vbase + (16 + c) * 2048 + q * 8);
    half8_t vf10 = *reinterpret_cast<const half8_t*>(vbase + 32 + c * 2048 + q * 8);
    half8_t vf11 = *reinterpret_cast<const half8_t*>(vbase + 32 + (16 + c) * 2048 + q * 8);
    f32x4 sA00 = __builtin_amdgcn_mfma_f32_16x16x32_f16(qfA, kf00, z4, 0, 0, 0);
    f32x4 sA01 = __builtin_amdgcn_mfma_f32_16x16x32_f16(qfA, kf01, z4, 0, 0, 0);
    f32x4 sB00 = __builtin_amdgcn_mfma_f32_16x16x32_f16(qfB, kf00, z4, 0, 0, 0);
    f32x4 sB01 = __builtin_amdgcn_mfma_f32_16x16x32_f16(qfB, kf01, z4, 0, 0, 0);
    f32x4 sA10 = __builtin_amdgcn_mfma_f32_16x16x32_f16(qfA, kf10, z4, 0, 0, 0);
    f32x4 sA11 = __builtin_amdgcn_mfma_f32_16x16x32_f16(qfA, kf11, z4, 0, 0, 0);
    f32x4 sB10 = __builtin_amdgcn_mfma_f32_16x16x32_f16(qfB, kf10, z4, 0, 0, 0);
    f32x4 sB11 = __builtin_amdgcn_mfma_f32_16x16x32_f16(qfB, kf11, z4, 0, 0, 0);

    __syncthreads();   // barrier A: both bias buffers ready

    const _Float16* bR0 = biasH + w * 1160;
    const _Float16* bR1 = biasH + 9280 + w * 1160;
    half4_t bbA00 = *reinterpret_cast<const half4_t*>(bR0 + (2 * c) * 36 + q * 4);
    half4_t bbA01 = *reinterpret_cast<const half4_t*>(bR0 + (2 * c + 1) * 36 + q * 4);
    half4_t bbB00 = *reinterpret_cast<const half4_t*>(bR0 + (2 * c) * 36 + 16 + q * 4);
    half4_t bbB01 = *reinterpret_cast<const half4_t*>(bR0 + (2 * c + 1) * 36 + 16 + q * 4);
    half4_t bbA10 = *reinterpret_cast<const half4_t*>(bR1 + (2 * c) * 36 + q * 4);
    half4_t bbA11 = *reinterpret_cast<const half4_t*>(bR1 + (2 * c + 1) * 36 + q * 4);
    half4_t bbB10 = *reinterpret_cast<const half4_t*>(bR1 + (2 * c) * 36 + 16 + q * 4);
    half4_t bbB11 = *reinterpret_cast<const half4_t*>(bR1 + (2 * c + 1) * 36 + 16 + q * 4);

    // ---- stream A: both tiles, one trigger ----
    {
      float p00[4], p01[4], p10[4], p11[4], mr[4];
#pragma unroll
      for (int r = 0; r < 4; ++r) {
        const float sv00 = sA00[r] * KSCALE + (float)bbA00[r];
        const float sv01 = sA01[r] * KSCALE + (float)bbA01[r];
        const float sv10 = sA10[r] * KSCALE + (float)bbA10[r];
        const float sv11 = sA11[r] * KSCALE + (float)bbA11[r];
        mr[r] = fmaxf(fmaxf(sv00, sv01), fmaxf(sv10, sv11));
        p00[r] = EXP2F(sv00 - mA[r]);
        p01[r] = EXP2F(sv01 - mA[r]);
        p10[r] = EXP2F(sv10 - mA[r]);
        p11[r] = EXP2F(sv11 - mA[r]);
      }
      float need = fmaxf(fmaxf(mr[0] - mA[0], mr[1] - mA[1]),
                         fmaxf(mr[2] - mA[2], mr[3] - mA[3]));
      if (__any(need > 4.0f)) {   // rare: row reduce + rescale + p-fix
        h2 pk01, pk23;
        pk01[0] = (_Float16)mr[0]; pk01[1] = (_Float16)mr[1];
        pk23[0] = (_Float16)mr[2]; pk23[1] = (_Float16)mr[3];
        pk01 = rowmax16_h2(pk01);
        pk23 = rowmax16_h2(pk23);
        float mred[4] = {(float)pk01[0], (float)pk01[1],
                         (float)pk23[0], (float)pk23[1]};
#pragma unroll
        for (int r = 0; r < 4; ++r) {
          const float mnew = fmaxf(mA[r], mred[r]);
          const float alpha = EXP2F(mA[r] - mnew);
          p00[r] *= alpha; p01[r] *= alpha;
          p10[r] *= alpha; p11[r] *= alpha;
          lpA[r] *= alpha;
          O0A[r] *= alpha; O1A[r] *= alpha;
          mA[r] = mnew;
        }
      }
#pragma unroll
      for (int r = 0; r < 4; ++r) {
        h2 pp0; pp0[0] = (_Float16)p00[r]; pp0[1] = (_Float16)p01[r];
        *reinterpret_cast<h2*>(pb + (q * 4 + r) * 32 + 2 * c) = pp0;
        h2 pp1; pp1[0] = (_Float16)p10[r]; pp1[1] = (_Float16)p11[r];
        *reinterpret_cast<h2*>(pb + 512 + (q * 4 + r) * 32 + 2 * c) = pp1;
      }
    }
    // ---- stream B: both tiles, one trigger ----
    {
      float p00[4], p01[4], p10[4], p11[4], mr[4];
#pragma unroll
      for (int r = 0; r < 4; ++r) {
        const float sv00 = sB00[r] * KSCALE + (float)bbB00[r];
        const float sv01 = sB01[r] * KSCALE + (float)bbB01[r];
        const float sv10 = sB10[r] * KSCALE + (float)bbB10[r];
        const float sv11 = sB11[r] * KSCALE + (float)bbB11[r];
        mr[r] = fmaxf(fmaxf(sv00, sv01), fmaxf(sv10, sv11));
        p00[r] = EXP2F(sv00 - mB[r]);
        p01[r] = EXP2F(sv01 - mB[r]);
        p10[r] = EXP2F(sv10 - mB[r]);
        p11[r] = EXP2F(sv11 - mB[r]);
      }
      float need = fmaxf(fmaxf(mr[0] - mB[0], mr[1] - mB[1]),
                         fmaxf(mr[2] - mB[2], mr[3] - mB[3]));
      if (__any(need > 4.0f)) {
        h2 pk01, pk23;
        pk01[0] = (_Float16)mr[0]; pk01[1] = (_Float16)mr[1];
        pk23[0] = (_Float16)mr[2]; pk23[1] = (_Float16)mr[3];
        pk01 = rowmax16_h2(pk01);
        pk23 = rowmax16_h2(pk23);
        float mred[4] = {(float)pk01[0], (float)pk01[1],
                         (float)pk23[0], (float)pk23[1]};
#pragma unroll
        for (int r = 0; r < 4; ++r) {
          const float mnew = fmaxf(mB[r], mred[r]);
          const float alpha = EXP2F(mB[r] - mnew);
          p00[r] *= alpha; p01[r] *= alpha;
          p10[r] *= alpha; p11[r] *= alpha;
          lpB[r] *= alpha;
          O0B[r] *= alpha; O1B[r] *= alpha;
          mB[r] = mnew;
        }
      }
#pragma unroll
      for (int r = 0; r < 4; ++r) {
        h2 pp0; pp0[0] = (_Float16)p00[r]; pp0[1] = (_Float16)p01[r];
        *reinterpret_cast<h2*>(pb + 1024 + (q * 4 + r) * 32 + 2 * c) = pp0;
        h2 pp1; pp1[0] = (_Float16)p10[r]; pp1[1] = (_Float16)p11[r];
        *reinterpret_cast<h2*>(pb + 1536 + (q * 4 + r) * 32 + 2 * c) = pp1;
      }
    }

    // wave-private pbuf: order writes before reads (LDS only — no vmcnt drain)
    asm volatile("s_waitcnt lgkmcnt(0)" ::: "memory");
    __builtin_amdgcn_sched_barrier(0);

    half8_t pfA0 = *reinterpret_cast<const half8_t*>(pb + c * 32 + q * 8);
    half8_t pfA1 = *reinterpret_cast<const half8_t*>(pb + 512 + c * 32 + q * 8);
    half8_t pfB0 = *reinterpret_cast<const half8_t*>(pb + 1024 + c * 32 + q * 8);
    half8_t pfB1 = *reinterpret_cast<const half8_t*>(pb + 1536 + c * 32 + q * 8);
    O0A = __builtin_amdgcn_mfma_f32_16x16x32_f16(pfA0, vf00, O0A, 0, 0, 0);
    O1A = __builtin_amdgcn_mfma_f32_16x16x32_f16(pfA0, vf01, O1A, 0, 0, 0);
    O0A = __builtin_amdgcn_mfma_f32_16x16x32_f16(pfA1, vf10, O0A, 0, 0, 0);
    O1A = __builtin_amdgcn_mfma_f32_16x16x32_f16(pfA1, vf11, O1A, 0, 0, 0);
    O0B = __builtin_amdgcn_mfma_f32_16x16x32_f16(pfB0, vf00, O0B, 0, 0, 0);
    O1B = __builtin_amdgcn_mfma_f32_16x16x32_f16(pfB0, vf01, O1B, 0, 0, 0);
    O0B = __builtin_amdgcn_mfma_f32_16x16x32_f16(pfB1, vf10, O0B, 0, 0, 0);
    O1B = __builtin_amdgcn_mfma_f32_16x16x32_f16(pfB1, vf11, O1B, 0, 0, 0);
    lpA = __builtin_amdgcn_mfma_f32_16x16x32_f16(pfA0, ones8, lpA, 0, 0, 0);
    lpA = __builtin_amdgcn_mfma_f32_16x16x32_f16(pfA1, ones8, lpA, 0, 0, 0);
    lpB = __builtin_amdgcn_mfma_f32_16x16x32_f16(pfB0, ones8, lpB, 0, 0, 0);
    lpB = __builtin_amdgcn_mfma_f32_16x16x32_f16(pfB1, ones8, lpB, 0, 0, 0);

    __syncthreads();   // barrier B: WAR before next pair's bias writes
  }

  // ---- finalize: lp already full row sums (ones-MFMA); no lane reduce ----
#pragma unroll
  for (int r = 0; r < 4; ++r) {
    const float s = lpA[r];
    const float inv = 1.f / s;
    const int n = i0 + q * 4 + r;
    const long base = (long)(((chunk * 2 + b) * 8 + w) * 2048 + n);
    Opart[base * 32 + c]      = (_Float16)(O0A[r] * inv);
    Opart[base * 32 + 16 + c] = (_Float16)(O1A[r] * inv);
    if (c == 0) Mpart[base] = mA[r] + __log2f(s);
  }
#pragma unroll
  for (int r = 0; r < 4; ++r) {
    const float s = lpB[r];
    const float inv = 1.f / s;
    const int n = i0 + 16 + q * 4 + r;
    const long base = (long)(((chunk * 2 + b) * 8 + w) * 2048 + n);
    Opart[base * 32 + c]      = (_Float16)(O0B[r] * inv);
    Opart[base * 32 + 16 + c] = (_Float16)(O1B[r] * inv);
    if (c == 0) Mpart[base] = mB[r] + __log2f(s);
  }
}

// ---------------------------------------------------------------------------
// combine_proj: fused. Phase 1: merge 4 j-chunk partials for 16 rows into
// LDS [16][264] f16. Phase 2: proj GEMM out = attn @ W_out + b_out, A from
// LDS. (nck reverted to 4 — 8 chunks showed no flash gain, cost 8 MB.)
// ---------------------------------------------------------------------------
__global__ __launch_bounds__(256) void combine_proj(
    const _Float16* __restrict__ Opart, const float* __restrict__ Mpart,
    const _Float16* __restrict__ WoutT, const float* __restrict__ bout,
    float* __restrict__ out)
{
  __shared__ _Float16 aT[16][264];   // 16 rows x 256 cols, +8 pad
  const int i0 = blockIdx.x * 16;    // global row in [0,4096)
  const int b = i0 >> 11;
  const int n0 = i0 & 2047;
  const int tid = threadIdx.x;
  {
    const int row = tid >> 4, cg = tid & 15;   // col group: cols cg*16..+15
    const int n = n0 + row;
    const int h = cg >> 1;
    const int d0 = (cg & 1) * 16;
    float mv[4], M = -INFINITY;
#pragma unroll
    for (int ck = 0; ck < 4; ++ck) {
      mv[ck] = Mpart[((ck * 2 + b) * 8 + h) * 2048 + n];
      M = fmaxf(M, mv[ck]);
    }
    float num[16];
#pragma unroll
    for (int e = 0; e < 16; ++e) num[e] = 0.f;
    float den = 0.f;
#pragma unroll
    for (int ck = 0; ck < 4; ++ck) {
      const float wgt = EXP2F(mv[ck] - M);
      const _Float16* op = Opart +
          (long)(((ck * 2 + b) * 8 + h) * 2048 + n) * 32 + d0;
      half8_t o0v = *reinterpret_cast<const half8_t*>(op);
      half8_t o1v = *reinterpret_cast<const half8_t*>(op + 8);
#pragma unroll
      for (int e = 0; e < 8; ++e) {
        num[e]     += wgt * (float)o0v[e];
        num[8 + e] += wgt * (float)o1v[e];
      }
      den += wgt;
    }
    const float inv = 1.f / den;
    half8_t h0, h1;
#pragma unroll
    for (int e = 0; e < 8; ++e) {
      h0[e] = (_Float16)(num[e] * inv);
      h1[e] = (_Float16)(num[8 + e] * inv);
    }
    *reinterpret_cast<half8_t*>(&aT[row][cg * 16])     = h0;
    *reinterpret_cast<half8_t*>(&aT[row][cg * 16 + 8]) = h1;
  }
  __syncthreads();

  // ---- proj GEMM: wave does 16i x 64o (4 tiles), A from LDS ----
  const int o0 = (tid >> 6) * 64;
  const int lane = tid & 63, q = lane >> 4, c = lane & 15;
  f32x4 acc[4] = {{0,0,0,0},{0,0,0,0},{0,0,0,0},{0,0,0,0}};
  const _Float16* brow = WoutT + (o0 + c) * 256;
#pragma unroll
  for (int k0 = 0; k0 < 256; k0 += 32) {
    half8_t af = *reinterpret_cast<const half8_t*>(&aT[c][k0 + q * 8]);
#pragma unroll
    for (int t = 0; t < 4; ++t) {
      half8_t bf = *reinterpret_cast<const half8_t*>(brow + t * 16 * 256 + k0 + q * 8);
      acc[t] = __builtin_amdgcn_mfma_f32_16x16x32_f16(af, bf, acc[t], 0, 0, 0);
    }
  }
#pragma unroll
  for (int t = 0; t < 4; ++t) {
    const float bo = bout[o0 + t * 16 + c];
#pragma unroll
    for (int r = 0; r < 4; ++r)
      out[(i0 + q * 4 + r) * 256 + o0 + t * 16 + c] = acc[t][r] + bo;
  }
}

// ---------------------------------------------------------------------------
extern "C" void kernel_launch(void* const* d_in, const int* in_sizes, int n_in,
                              void* d_out, int out_size, void* d_ws, size_t ws_size,
                              hipStream_t stream)
{
  const float* x      = (const float*)d_in[0];
  const float* coords = (const float*)d_in[1];
  const float* Wqkv   = (const float*)d_in[2];
  const float* Wout   = (const float*)d_in[3];
  const float* bout   = (const float*)d_in[4];
  const float* pw1    = (const float*)d_in[5];
  const float* pb1    = (const float*)d_in[6];
  const float* pw2    = (const float*)d_in[7];
  const float* sw1    = (const float*)d_in[9];
  const float* sb1    = (const float*)d_in[10];
  const float* sw2    = (const float*)d_in[11];
  float* out = (float*)d_out;

  char* ws = (char*)d_ws;
  _Float16* Qh      = (_Float16*)(ws + 0);         // 2 MB
  _Float16* Kh      = (_Float16*)(ws + 2097152);   // 2 MB
  _Float16* Vt      = (_Float16*)(ws + 4194304);   // 2 MB
  _Float16* xf16    = (_Float16*)(ws + 6291456);   // 2 MB (dead after qkv_gemm)
  _Float16* WqkvT   = (_Float16*)(ws + 8388608);   // 384 KB
  _Float16* WoutT   = (_Float16*)(ws + 8781824);   // 128 KB
  _Float16* APre    = (_Float16*)(ws + 8912896);   // 256 KB
  _Float16* BPre    = (_Float16*)(ws + 9175040);   // 256 KB
  _Float16* Opart   = (_Float16*)(ws + 9437184);   // 8 MB  [4][2][8][2048][32]
  float*    Mpart   = (float*)   (ws + 17825792);  // 512 KB [4][2][8][2048]

  prep_misc<<<1104, 256, 0, stream>>>(x, Wqkv, Wout, coords, pw1, pb1, sw1, sb1,
                                      xf16, WqkvT, WoutT, APre, BPre);
  qkv_gemm<<<768, 256, 0, stream>>>(xf16, WqkvT, Qh, Kh, Vt);
  flash<<<512, 512, 0, stream>>>(Qh, Kh, Vt, APre, BPre, pw2, sw2, Opart, Mpart);
  combine_proj<<<256, 256, 0, stream>>>(Opart, Mpart, WoutT, bout, out);
}

// Round 7
// 170.390 us; speedup vs baseline: 1.1690x; 1.1690x over previous
//
#include <hip/hip_runtime.h>
#include <hip/hip_fp16.h>

// ---------------- types ----------------
typedef _Float16 half8_t __attribute__((ext_vector_type(8)));
typedef _Float16 half4_t __attribute__((ext_vector_type(4)));
typedef _Float16 h2      __attribute__((ext_vector_type(2)));
typedef float    f32x4   __attribute__((ext_vector_type(4)));

#define LOG2E 1.4426950408889634f
// SCALE = 1/sqrt(32); fold log2(e) so we can use exp2
#define KSCALE (0.17677669529663687f * LOG2E)

#if __has_builtin(__builtin_amdgcn_exp2f)
#define EXP2F(x) __builtin_amdgcn_exp2f(x)
#else
#define EXP2F(x) exp2f(x)
#endif

// DPP row_ror:N (rotate within 16-lane row) — VALU cross-lane, no LDS pipe.
template <int N>
__device__ __forceinline__ int dpp_ror(int v) {
  return __builtin_amdgcn_update_dpp(0, v, 0x120 + N, 0xf, 0xf, true);
}
// 16-lane max-reduce of two independent f16 values packed in h2.
__device__ __forceinline__ h2 rowmax16_h2(h2 v) {
  int t;
  t = dpp_ror<1>(__builtin_bit_cast(int, v));
  v = __builtin_elementwise_max(v, __builtin_bit_cast(h2, t));
  t = dpp_ror<2>(__builtin_bit_cast(int, v));
  v = __builtin_elementwise_max(v, __builtin_bit_cast(h2, t));
  t = dpp_ror<4>(__builtin_bit_cast(int, v));
  v = __builtin_elementwise_max(v, __builtin_bit_cast(h2, t));
  t = dpp_ror<8>(__builtin_bit_cast(int, v));
  v = __builtin_elementwise_max(v, __builtin_bit_cast(h2, t));
  return v;
}

// ---------------------------------------------------------------------------
// prep: [0,1024)   x -> f16 (vector cast)
//       [1024,1072) Wqkv^T via LDS 64x64 tile transpose (4 k-tiles x 12 o-tiles)
//       [1072,1088) Wout^T via LDS tile transpose (16 tiles)
//       [1088,1104) coords layer-1 precompute
// ---------------------------------------------------------------------------
__global__ __launch_bounds__(256) void prep_misc(
    const float* __restrict__ x, const float* __restrict__ Wqkv,
    const float* __restrict__ Wout, const float* __restrict__ coords,
    const float* __restrict__ pw1, const float* __restrict__ pb1,
    const float* __restrict__ sw1, const float* __restrict__ sb1,
    _Float16* __restrict__ xf16, _Float16* __restrict__ WqkvT,
    _Float16* __restrict__ WoutT, _Float16* __restrict__ APre,
    _Float16* __restrict__ BPre)
{
  __shared__ float tile[64][65];
  const int bi = blockIdx.x, tid = threadIdx.x;
  if (bi < 1024) {                       // x cast: 1,048,576 floats
    const int idx = bi * 256 + tid;
    f32x4 v = *reinterpret_cast<const f32x4*>(x + idx * 4);
    half4_t h;
    h[0] = (_Float16)v[0]; h[1] = (_Float16)v[1];
    h[2] = (_Float16)v[2]; h[3] = (_Float16)v[3];
    *reinterpret_cast<half4_t*>(xf16 + idx * 4) = h;
  } else if (bi < 1088) {                // W transposes, 64x64 tiles
    const float* src; _Float16* dst; int t, W;  // W = src row width
    if (bi < 1072) { t = bi - 1024; src = Wqkv; dst = WqkvT; W = 768; }
    else           { t = bi - 1072; src = Wout; dst = WoutT; W = 256; }
    const int nOT = W >> 6;              // o-tiles per k-row
    const int tk = t / nOT, to = t % nOT;
    const int cx = tid & 63, ry = tid >> 6;
#pragma unroll
    for (int rr = 0; rr < 16; ++rr) {
      const int kl = rr * 4 + ry;
      tile[kl][cx] = src[(tk * 64 + kl) * W + to * 64 + cx];
    }
    __syncthreads();
#pragma unroll
    for (int rr = 0; rr < 16; ++rr) {
      const int ol = rr * 4 + ry;
      dst[(to * 64 + ol) * 256 + tk * 64 + cx] = (_Float16)tile[cx][ol];
    }
  } else {                               // coords precompute: 4096 rows
    const int row = (bi - 1088) * 256 + tid;
    const float c0 = coords[row * 3 + 0];
    const float c1 = coords[row * 3 + 1];
    const float c2 = coords[row * 3 + 2];
#pragma unroll
    for (int k = 0; k < 16; ++k) {
      float a = c0 * pw1[k] + c1 * pw1[16 + k] + c2 * pw1[32 + k];
      APre[row * 32 + k] = (_Float16)(a + pb1[k]);
      BPre[row * 32 + k] = (_Float16)a;
      float s  =  c0 * sw1[k] + c1 * sw1[16 + k] + c2 * sw1[32 + k];
      float sb = -c0 * sw1[k] + c1 * sw1[16 + k] + c2 * sw1[32 + k];
      APre[row * 32 + 16 + k] = (_Float16)(s + sb1[k]);
      BPre[row * 32 + 16 + k] = (_Float16)sb;
    }
  }
}

// ---------------------------------------------------------------------------
// qkv_gemm: [4096x768] = xf16[4096x256] @ Wqkv; wave does 16i x 64o (4 tiles,
// A-fragment reused 4x). Epilogue: Q/K coalesced scatter (32B segments);
// V through a per-wave LDS transpose -> per-lane 16B row stores (round-6 win).
// ---------------------------------------------------------------------------
__global__ __launch_bounds__(256) void qkv_gemm(
    const _Float16* __restrict__ xf16, const _Float16* __restrict__ WqkvT,
    _Float16* __restrict__ Qh, _Float16* __restrict__ Kh,
    _Float16* __restrict__ Vt)
{
  __shared__ _Float16 vtile[4][64][24];   // per-wave 64o x 16n tile, stride 24
  const int wv = threadIdx.x >> 6;
  const int wg = blockIdx.x * 4 + wv;
  const int ti = wg / 12, og = wg % 12;
  const int i0 = ti * 16, o0 = og * 64;
  const int lane = threadIdx.x & 63, q = lane >> 4, c = lane & 15;
  f32x4 acc[4] = {{0,0,0,0},{0,0,0,0},{0,0,0,0},{0,0,0,0}};
  const _Float16* arow = xf16 + (i0 + c) * 256;
  const _Float16* brow = WqkvT + (o0 + c) * 256;
#pragma unroll
  for (int k0 = 0; k0 < 256; k0 += 32) {
    half8_t af = *reinterpret_cast<const half8_t*>(arow + k0 + q * 8);
#pragma unroll
    for (int t = 0; t < 4; ++t) {
      half8_t bf = *reinterpret_cast<const half8_t*>(brow + t * 16 * 256 + k0 + q * 8);
      acc[t] = __builtin_amdgcn_mfma_f32_16x16x32_f16(af, bf, acc[t], 0, 0, 0);
    }
  }
  const int b = i0 >> 11, n0 = i0 & 2047;
  if (og < 8) {                          // Q / K epilogue
#pragma unroll
    for (int t = 0; t < 4; ++t) {
      const int o = o0 + t * 16 + c;
      const int which = o >> 8, h = (o >> 5) & 7, d = o & 31;
#pragma unroll
      for (int r = 0; r < 4; ++r) {
        const int n = n0 + q * 4 + r;
        _Float16 v = (_Float16)acc[t][r];
        if (which == 0) Qh[((b * 8 + h) * 2048 + n) * 32 + d] = v;
        else            Kh[((b * 8 + h) * 2048 + n) * 32 + d] = v;
      }
    }
  } else {                               // V epilogue via LDS transpose
    _Float16* vt = &vtile[wv][0][0];
#pragma unroll
    for (int t = 0; t < 4; ++t)
#pragma unroll
      for (int r = 0; r < 4; ++r)
        vt[(t * 16 + c) * 24 + q * 4 + r] = (_Float16)acc[t][r];
    asm volatile("s_waitcnt lgkmcnt(0)" ::: "memory");   // wave-private tile
    __builtin_amdgcn_sched_barrier(0);
    const long row = (long)(b * 256 + (o0 - 512) + lane);
    half8_t r0 = *reinterpret_cast<const half8_t*>(vt + lane * 24);
    half8_t r1 = *reinterpret_cast<const half8_t*>(vt + lane * 24 + 8);
    *reinterpret_cast<half8_t*>(Vt + row * 2048 + n0)     = r0;
    *reinterpret_cast<half8_t*>(Vt + row * 2048 + n0 + 8) = r1;
  }
}

// ---------------------------------------------------------------------------
// flash: grid = [b:2][chunk:4][itile:64]; block = 512 thr, wave w = head w.
// Two 16-row Q streams A/B per wave; single j-tile per iteration (the
// round-6 KVBLK=64 pair unroll spilled: ~200 regs needed vs 128 budget —
// reverted). Kept from round 6 (register-neutral):
//   * lp via ones-MFMA: row-sum of P on the matrix pipe (kills 16 VALU
//     adds/tile + the entire epilogue rowsum16 reduce).
//   * threadfence -> targeted s_waitcnt lgkmcnt(0) + sched_barrier(0).
// NOTE: __launch_bounds__(512,4) — (512,6) spilled (round 4). Occupancy is
// NOT the lever (round-5 nck=8 experiment: +TLP, no gain) — issue-bound.
// ---------------------------------------------------------------------------
__global__ __launch_bounds__(512, 4) void flash(
    const _Float16* __restrict__ Qh, const _Float16* __restrict__ Kh,
    const _Float16* __restrict__ Vt, const _Float16* __restrict__ APre,
    const _Float16* __restrict__ BPre, const float* __restrict__ pw2,
    const float* __restrict__ sw2, _Float16* __restrict__ Opart,
    float* __restrict__ Mpart)
{
  __shared__ __align__(16) unsigned char smem[53504];
  _Float16* biasH = reinterpret_cast<_Float16*>(smem);          // [2][8h*1160] f16
  _Float16* pbuf  = reinterpret_cast<_Float16*>(smem + 37120);  // [8w][2][16 x 32] f16

  const int blk = blockIdx.x;
  const int b     = blk >> 8;
  const int chunk = (blk >> 6) & 3;
  const int i0    = (blk & 63) << 5;
  const int tid = threadIdx.x;
  const int w = tid >> 6, lane = tid & 63;
  const int q = lane >> 4, c = lane & 15;

  // Q fragments (A-operand): stream A rows i0+c, stream B rows i0+16+c
  const _Float16* qbase = Qh + ((b * 8 + w) * 2048 + i0) * 32;
  half8_t qfA = *reinterpret_cast<const half8_t*>(qbase + c * 32 + q * 8);
  half8_t qfB = *reinterpret_cast<const half8_t*>(qbase + (16 + c) * 32 + q * 8);
  // APre fragments for bias-MFMA A side, j-invariant
  const _Float16* abase = APre + (b * 2048 + i0) * 32;
  half8_t apfA = *reinterpret_cast<const half8_t*>(abase + c * 32 + q * 8);
  half8_t apfB = *reinterpret_cast<const half8_t*>(abase + (16 + c) * 32 + q * 8);

  // stacked W2 B-fragment: B[k][n], k<16 -> pos_w2, k>=16 -> sym_w2; *LOG2E
  half8_t w2f;
#pragma unroll
  for (int jj = 0; jj < 8; ++jj) {
    const int k = q * 8 + jj;
    float val = 0.f;
    if (c < 8) val = (k < 16 ? pw2[k * 8 + c] : sw2[(k - 16) * 8 + c]) * LOG2E;
    w2f[jj] = (_Float16)val;
  }
  half8_t ones8;
#pragma unroll
  for (int jj = 0; jj < 8; ++jj) ones8[jj] = (_Float16)1.0f;

  float mA[4], mB[4];
  f32x4 O0A = {0,0,0,0}, O1A = {0,0,0,0}, O0B = {0,0,0,0}, O1B = {0,0,0,0};
  f32x4 lpA = {0,0,0,0}, lpB = {0,0,0,0};
#pragma unroll
  for (int r = 0; r < 4; ++r) { mA[r] = 0.f; mB[r] = 0.f; }  // m init 0 (exact)

  const f32x4 z4 = {0.f, 0.f, 0.f, 0.f};
  half8_t hzero8 = {};

  const int jbase = chunk * 512;
  const _Float16* BPre_b = BPre + (long)b * 2048 * 32;
  _Float16* pbA = pbuf + w * 1024;
  _Float16* pbB = pbA + 512;

  for (int jt = 0; jt < 16; ++jt) {
    const int j0 = jbase + jt * 32;
    _Float16* bW = biasH + (jt & 1) * 9280;

    // ---- bias: reg-resident hidden frags + MFMA; 4 j-cols x 2 i-halves ----
#pragma unroll
    for (int mt = 0; mt < 4; ++mt) {
      const int jl = w * 4 + mt;
      half8_t bpf = *reinterpret_cast<const half8_t*>(
          BPre_b + (j0 + jl) * 32 + q * 8);
      half8_t hvA = __builtin_elementwise_max(apfA - bpf, hzero8);
      f32x4 bcA = __builtin_amdgcn_mfma_f32_16x16x32_f16(hvA, w2f, z4, 0, 0, 0);
      half8_t hvB = __builtin_elementwise_max(apfB - bpf, hzero8);
      f32x4 bcB = __builtin_amdgcn_mfma_f32_16x16x32_f16(hvB, w2f, z4, 0, 0, 0);
      if (c < 8) {   // C cols 0..7 = heads; [h][j][i], j-stride 36, h-stride 1160
        half4_t b4;
        b4[0] = (_Float16)bcA[0]; b4[1] = (_Float16)bcA[1];
        b4[2] = (_Float16)bcA[2]; b4[3] = (_Float16)bcA[3];
        *reinterpret_cast<half4_t*>(bW + c * 1160 + jl * 36 + q * 4) = b4;
        half4_t b5;
        b5[0] = (_Float16)bcB[0]; b5[1] = (_Float16)bcB[1];
        b5[2] = (_Float16)bcB[2]; b5[3] = (_Float16)bcB[3];
        *reinterpret_cast<half4_t*>(bW + c * 1160 + jl * 36 + 16 + q * 4) = b5;
      }
    }

    // ---- K/V fragments; scores (independent of biasF) ----
    const _Float16* kbase = Kh + ((b * 8 + w) * 2048 + j0) * 32;
    half8_t kf0 = *reinterpret_cast<const half8_t*>(kbase + (2 * c) * 32 + q * 8);
    half8_t kf1 = *reinterpret_cast<const half8_t*>(kbase + (2 * c + 1) * 32 + q * 8);
    const _Float16* vbase = Vt + (b * 8 + w) * 65536 + j0;
    half8_t vf0 = *reinterpret_cast<const half8_t*>(vbase + c * 2048 + q * 8);
    half8_t vf1 = *reinterpret_cast<const half8_t*>(vbase + (16 + c) * 2048 + q * 8);
    f32x4 sA0 = __builtin_amdgcn_mfma_f32_16x16x32_f16(qfA, kf0, z4, 0, 0, 0);
    f32x4 sA1 = __builtin_amdgcn_mfma_f32_16x16x32_f16(qfA, kf1, z4, 0, 0, 0);
    f32x4 sB0 = __builtin_amdgcn_mfma_f32_16x16x32_f16(qfB, kf0, z4, 0, 0, 0);
    f32x4 sB1 = __builtin_amdgcn_mfma_f32_16x16x32_f16(qfB, kf1, z4, 0, 0, 0);

    __syncthreads();   // biasF[jt&1] ready (sole barrier this iteration)

    const _Float16* bR = biasH + (jt & 1) * 9280 + w * 1160;
    half4_t bbA0 = *reinterpret_cast<const half4_t*>(bR + (2 * c) * 36 + q * 4);
    half4_t bbA1 = *reinterpret_cast<const half4_t*>(bR + (2 * c + 1) * 36 + q * 4);
    half4_t bbB0 = *reinterpret_cast<const half4_t*>(bR + (2 * c) * 36 + 16 + q * 4);
    half4_t bbB1 = *reinterpret_cast<const half4_t*>(bR + (2 * c + 1) * 36 + 16 + q * 4);

    // ---- stream A online softmax (rows i0 + q*4+r, j = 2c,2c+1) ----
    {
      float sv0[4], sv1[4], p0[4], p1[4], mr[4];
#pragma unroll
      for (int r = 0; r < 4; ++r) {
        sv0[r] = sA0[r] * KSCALE + (float)bbA0[r];
        sv1[r] = sA1[r] * KSCALE + (float)bbA1[r];
        mr[r] = fmaxf(sv0[r], sv1[r]);
      }
      // exp2 on TRANS pipe; no cross-lane work on the common path
#pragma unroll
      for (int r = 0; r < 4; ++r) {
        p0[r] = EXP2F(sv0[r] - mA[r]);
        p1[r] = EXP2F(sv1[r] - mA[r]);
      }
      // lane-local trigger: identical to row-reduced trigger under __any
      float need = fmaxf(fmaxf(mr[0] - mA[0], mr[1] - mA[1]),
                         fmaxf(mr[2] - mA[2], mr[3] - mA[3]));
      if (__any(need > 4.0f)) {   // rare: full row reduce + rescale + p-fix
        h2 pk01, pk23;
        pk01[0] = (_Float16)mr[0]; pk01[1] = (_Float16)mr[1];
        pk23[0] = (_Float16)mr[2]; pk23[1] = (_Float16)mr[3];
        pk01 = rowmax16_h2(pk01);
        pk23 = rowmax16_h2(pk23);
        float mred[4] = {(float)pk01[0], (float)pk01[1],
                         (float)pk23[0], (float)pk23[1]};
#pragma unroll
        for (int r = 0; r < 4; ++r) {
          const float mnew = fmaxf(mA[r], mred[r]);
          const float alpha = EXP2F(mA[r] - mnew);
          p0[r] *= alpha; p1[r] *= alpha;
          lpA[r] *= alpha;
          O0A[r] *= alpha; O1A[r] *= alpha;
          mA[r] = mnew;
        }
      }
#pragma unroll
      for (int r = 0; r < 4; ++r) {
        h2 pp; pp[0] = (_Float16)p0[r]; pp[1] = (_Float16)p1[r];
        *reinterpret_cast<h2*>(pbA + (q * 4 + r) * 32 + 2 * c) = pp;
      }
    }
    // ---- stream B online softmax (rows i0+16 + q*4+r) ----
    {
      float sv0[4], sv1[4], p0[4], p1[4], mr[4];
#pragma unroll
      for (int r = 0; r < 4; ++r) {
        sv0[r] = sB0[r] * KSCALE + (float)bbB0[r];
        sv1[r] = sB1[r] * KSCALE + (float)bbB1[r];
        mr[r] = fmaxf(sv0[r], sv1[r]);
      }
#pragma unroll
      for (int r = 0; r < 4; ++r) {
        p0[r] = EXP2F(sv0[r] - mB[r]);
        p1[r] = EXP2F(sv1[r] - mB[r]);
      }
      float need = fmaxf(fmaxf(mr[0] - mB[0], mr[1] - mB[1]),
                         fmaxf(mr[2] - mB[2], mr[3] - mB[3]));
      if (__any(need > 4.0f)) {
        h2 pk01, pk23;
        pk01[0] = (_Float16)mr[0]; pk01[1] = (_Float16)mr[1];
        pk23[0] = (_Float16)mr[2]; pk23[1] = (_Float16)mr[3];
        pk01 = rowmax16_h2(pk01);
        pk23 = rowmax16_h2(pk23);
        float mred[4] = {(float)pk01[0], (float)pk01[1],
                         (float)pk23[0], (float)pk23[1]};
#pragma unroll
        for (int r = 0; r < 4; ++r) {
          const float mnew = fmaxf(mB[r], mred[r]);
          const float alpha = EXP2F(mB[r] - mnew);
          p0[r] *= alpha; p1[r] *= alpha;
          lpB[r] *= alpha;
          O0B[r] *= alpha; O1B[r] *= alpha;
          mB[r] = mnew;
        }
      }
#pragma unroll
      for (int r = 0; r < 4; ++r) {
        h2 pp; pp[0] = (_Float16)p0[r]; pp[1] = (_Float16)p1[r];
        *reinterpret_cast<h2*>(pbB + (q * 4 + r) * 32 + 2 * c) = pp;
      }
    }

    // wave-private pbuf: order writes before reads (LDS only — no vmcnt drain)
    asm volatile("s_waitcnt lgkmcnt(0)" ::: "memory");
    __builtin_amdgcn_sched_barrier(0);

    half8_t pfA = *reinterpret_cast<const half8_t*>(pbA + c * 32 + q * 8);
    half8_t pfB = *reinterpret_cast<const half8_t*>(pbB + c * 32 + q * 8);
    O0A = __builtin_amdgcn_mfma_f32_16x16x32_f16(pfA, vf0, O0A, 0, 0, 0);
    O1A = __builtin_amdgcn_mfma_f32_16x16x32_f16(pfA, vf1, O1A, 0, 0, 0);
    O0B = __builtin_amdgcn_mfma_f32_16x16x32_f16(pfB, vf0, O0B, 0, 0, 0);
    O1B = __builtin_amdgcn_mfma_f32_16x16x32_f16(pfB, vf1, O1B, 0, 0, 0);
    lpA = __builtin_amdgcn_mfma_f32_16x16x32_f16(pfA, ones8, lpA, 0, 0, 0);
    lpB = __builtin_amdgcn_mfma_f32_16x16x32_f16(pfB, ones8, lpB, 0, 0, 0);
  }

  // ---- finalize: lp already full row sums (ones-MFMA); no lane reduce ----
#pragma unroll
  for (int r = 0; r < 4; ++r) {
    const float s = lpA[r];
    const float inv = 1.f / s;
    const int n = i0 + q * 4 + r;
    const long base = (long)(((chunk * 2 + b) * 8 + w) * 2048 + n);
    Opart[base * 32 + c]      = (_Float16)(O0A[r] * inv);
    Opart[base * 32 + 16 + c] = (_Float16)(O1A[r] * inv);
    if (c == 0) Mpart[base] = mA[r] + __log2f(s);
  }
#pragma unroll
  for (int r = 0; r < 4; ++r) {
    const float s = lpB[r];
    const float inv = 1.f / s;
    const int n = i0 + 16 + q * 4 + r;
    const long base = (long)(((chunk * 2 + b) * 8 + w) * 2048 + n);
    Opart[base * 32 + c]      = (_Float16)(O0B[r] * inv);
    Opart[base * 32 + 16 + c] = (_Float16)(O1B[r] * inv);
    if (c == 0) Mpart[base] = mB[r] + __log2f(s);
  }
}

// ---------------------------------------------------------------------------
// combine_proj: fused. Phase 1: merge 4 j-chunk partials for 16 rows into
// LDS [16][264] f16. Phase 2: proj GEMM out = attn @ W_out + b_out, A from
// LDS. Saves the attnF16 HBM round-trip and one dispatch.
// ---------------------------------------------------------------------------
__global__ __launch_bounds__(256) void combine_proj(
    const _Float16* __restrict__ Opart, const float* __restrict__ Mpart,
    const _Float16* __restrict__ WoutT, const float* __restrict__ bout,
    float* __restrict__ out)
{
  __shared__ _Float16 aT[16][264];   // 16 rows x 256 cols, +8 pad
  const int i0 = blockIdx.x * 16;    // global row in [0,4096)
  const int b = i0 >> 11;
  const int n0 = i0 & 2047;
  const int tid = threadIdx.x;
  {
    const int row = tid >> 4, cg = tid & 15;   // col group: cols cg*16..+15
    const int n = n0 + row;
    const int h = cg >> 1;
    const int d0 = (cg & 1) * 16;
    float mv[4], M = -INFINITY;
#pragma unroll
    for (int ck = 0; ck < 4; ++ck) {
      mv[ck] = Mpart[((ck * 2 + b) * 8 + h) * 2048 + n];
      M = fmaxf(M, mv[ck]);
    }
    float num[16];
#pragma unroll
    for (int e = 0; e < 16; ++e) num[e] = 0.f;
    float den = 0.f;
#pragma unroll
    for (int ck = 0; ck < 4; ++ck) {
      const float wgt = EXP2F(mv[ck] - M);
      const _Float16* op = Opart +
          (long)(((ck * 2 + b) * 8 + h) * 2048 + n) * 32 + d0;
      half8_t o0v = *reinterpret_cast<const half8_t*>(op);
      half8_t o1v = *reinterpret_cast<const half8_t*>(op + 8);
#pragma unroll
      for (int e = 0; e < 8; ++e) {
        num[e]     += wgt * (float)o0v[e];
        num[8 + e] += wgt * (float)o1v[e];
      }
      den += wgt;
    }
    const float inv = 1.f / den;
    half8_t h0, h1;
#pragma unroll
    for (int e = 0; e < 8; ++e) {
      h0[e] = (_Float16)(num[e] * inv);
      h1[e] = (_Float16)(num[8 + e] * inv);
    }
    *reinterpret_cast<half8_t*>(&aT[row][cg * 16])     = h0;
    *reinterpret_cast<half8_t*>(&aT[row][cg * 16 + 8]) = h1;
  }
  __syncthreads();

  // ---- proj GEMM: wave does 16i x 64o (4 tiles), A from LDS ----
  const int o0 = (tid >> 6) * 64;
  const int lane = tid & 63, q = lane >> 4, c = lane & 15;
  f32x4 acc[4] = {{0,0,0,0},{0,0,0,0},{0,0,0,0},{0,0,0,0}};
  const _Float16* brow = WoutT + (o0 + c) * 256;
#pragma unroll
  for (int k0 = 0; k0 < 256; k0 += 32) {
    half8_t af = *reinterpret_cast<const half8_t*>(&aT[c][k0 + q * 8]);
#pragma unroll
    for (int t = 0; t < 4; ++t) {
      half8_t bf = *reinterpret_cast<const half8_t*>(brow + t * 16 * 256 + k0 + q * 8);
      acc[t] = __builtin_amdgcn_mfma_f32_16x16x32_f16(af, bf, acc[t], 0, 0, 0);
    }
  }
#pragma unroll
  for (int t = 0; t < 4; ++t) {
    const float bo = bout[o0 + t * 16 + c];
#pragma unroll
    for (int r = 0; r < 4; ++r)
      out[(i0 + q * 4 + r) * 256 + o0 + t * 16 + c] = acc[t][r] + bo;
  }
}

// ---------------------------------------------------------------------------
extern "C" void kernel_launch(void* const* d_in, const int* in_sizes, int n_in,
                              void* d_out, int out_size, void* d_ws, size_t ws_size,
                              hipStream_t stream)
{
  const float* x      = (const float*)d_in[0];
  const float* coords = (const float*)d_in[1];
  const float* Wqkv   = (const float*)d_in[2];
  const float* Wout   = (const float*)d_in[3];
  const float* bout   = (const float*)d_in[4];
  const float* pw1    = (const float*)d_in[5];
  const float* pb1    = (const float*)d_in[6];
  const float* pw2    = (const float*)d_in[7];
  const float* sw1    = (const float*)d_in[9];
  const float* sb1    = (const float*)d_in[10];
  const float* sw2    = (const float*)d_in[11];
  float* out = (float*)d_out;

  char* ws = (char*)d_ws;
  _Float16* Qh      = (_Float16*)(ws + 0);         // 2 MB
  _Float16* Kh      = (_Float16*)(ws + 2097152);   // 2 MB
  _Float16* Vt      = (_Float16*)(ws + 4194304);   // 2 MB
  _Float16* xf16    = (_Float16*)(ws + 6291456);   // 2 MB (dead after qkv_gemm)
  _Float16* WqkvT   = (_Float16*)(ws + 8388608);   // 384 KB
  _Float16* WoutT   = (_Float16*)(ws + 8781824);   // 128 KB
  _Float16* APre    = (_Float16*)(ws + 8912896);   // 256 KB
  _Float16* BPre    = (_Float16*)(ws + 9175040);   // 256 KB
  _Float16* Opart   = (_Float16*)(ws + 9437184);   // 8 MB  [4][2][8][2048][32]
  float*    Mpart   = (float*)   (ws + 17825792);  // 512 KB [4][2][8][2048]

  prep_misc<<<1104, 256, 0, stream>>>(x, Wqkv, Wout, coords, pw1, pb1, sw1, sb1,
                                      xf16, WqkvT, WoutT, APre, BPre);
  qkv_gemm<<<768, 256, 0, stream>>>(xf16, WqkvT, Qh, Kh, Vt);
  flash<<<512, 512, 0, stream>>>(Qh, Kh, Vt, APre, BPre, pw2, sw2, Opart, Mpart);
  combine_proj<<<256, 256, 0, stream>>>(Opart, Mpart, WoutT, bout, out);
}